// Round 2
// baseline (557.404 us; speedup 1.0000x reference)
//
#include <hip/hip_runtime.h>
#include <hip/hip_bf16.h>
#include <math.h>

// ---- problem constants ----
#define OUT_BF16 0   // reference computes float32; d_out is float*

static constexpr int BATCH = 1024;
static constexpr int NV = 6890;
static constexpr int NJ = 24;     // joints
static constexpr int NP = 207;    // pose features
static constexpr int NR = 19;     // regressed joints
static constexpr int V3 = NV * 3;
static constexpr int BT = 32;     // batches per K2 block

#if OUT_BF16
typedef __hip_bfloat16 outT;
__device__ __forceinline__ outT to_out(float x) { return __float2bfloat16(x); }
__device__ __forceinline__ float from_out(outT x) { return __bfloat162float(x); }
#else
typedef float outT;
__device__ __forceinline__ outT to_out(float x) { return x; }
__device__ __forceinline__ float from_out(outT x) { return x; }
#endif

// ---------------------------------------------------------------------------
// K0: batch-independent precompute:
//   SDJ[k][j][c] = sum_v shapedirs[k, v*3+c] * Jreg[v,j]   (10 x 24 x 3)
//   VTJ[j][c]    = sum_v v_template[v,c]     * Jreg[v,j]   (24 x 3)
// grid: 72 blocks (j*3+c), 256 threads
// ---------------------------------------------------------------------------
__global__ void k0_precompute(const float* __restrict__ sdirs,
                              const float* __restrict__ vtem,
                              const float* __restrict__ jreg,
                              float* __restrict__ SDJ,
                              float* __restrict__ VTJ) {
  const int jc = blockIdx.x;            // 0..71
  const int j = jc / 3, c = jc % 3;
  float acc[11];
#pragma unroll
  for (int k = 0; k < 11; ++k) acc[k] = 0.f;
  for (int v = threadIdx.x; v < NV; v += 256) {
    const float w = jreg[v * NJ + j];
    acc[10] += vtem[v * 3 + c] * w;
#pragma unroll
    for (int k = 0; k < 10; ++k) acc[k] += sdirs[(size_t)k * V3 + v * 3 + c] * w;
  }
  __shared__ float red[4][11];
  const int lane = threadIdx.x & 63, wv = threadIdx.x >> 6;
#pragma unroll
  for (int k = 0; k < 11; ++k) {
    float x = acc[k];
#pragma unroll
    for (int off = 32; off >= 1; off >>= 1) x += __shfl_down(x, off);
    if (lane == 0) red[wv][k] = x;
  }
  __syncthreads();
  if (threadIdx.x == 0) {
#pragma unroll
    for (int k = 0; k < 11; ++k) {
      const float s = red[0][k] + red[1][k] + red[2][k] + red[3][k];
      if (k < 10) SDJ[k * 72 + jc] = s;
      else        VTJ[jc] = s;
    }
  }
}

// ---------------------------------------------------------------------------
// K1: per batch: Jloc (via SDJ/VTJ), Rodrigues, pose_feature, kinematic chain,
//     A (3x4 per joint) and J_transformed output.
// grid: BATCH blocks, 128 threads
// ---------------------------------------------------------------------------
__global__ void k1_chain(const float* __restrict__ shape,
                         const float* __restrict__ pose,
                         const int* __restrict__ parents,
                         const float* __restrict__ SDJ,
                         const float* __restrict__ VTJ,
                         float* __restrict__ pf,    // [B][207]
                         float* __restrict__ Aout,  // [B][24][12] row-major 3x4
                         outT* __restrict__ out_jt) // [B][24][3]
{
  const int b = blockIdx.x;
  const int t = threadIdx.x;
  __shared__ float sh[10];
  __shared__ float Jl[NJ][3];
  __shared__ float Rm[NJ][9];
  __shared__ float G[NJ][12];
  if (t < 10) sh[t] = shape[b * 10 + t];
  __syncthreads();
  if (t < 72) {
    float s = VTJ[t];
#pragma unroll
    for (int k = 0; k < 10; ++k) s += sh[k] * SDJ[k * 72 + t];
    Jl[t / 3][t % 3] = s;
  }
  if (t < NJ) {
    const float px = pose[b * 72 + t * 3 + 0];
    const float py = pose[b * 72 + t * 3 + 1];
    const float pz = pose[b * 72 + t * 3 + 2];
    // reference: angle = ||pose + 1e-8||; r = pose / angle
    const float ax = px + 1e-8f, ay = py + 1e-8f, az = pz + 1e-8f;
    const float ang = sqrtf(ax * ax + ay * ay + az * az);
    const float inv = 1.f / ang;
    const float rx = px * inv, ry = py * inv, rz = pz * inv;
    const float cc = cosf(ang), ss = sinf(ang), mc = 1.f - cc;
    float R[9];
    R[0] = cc + mc * rx * rx;      R[1] = mc * rx * ry - ss * rz;  R[2] = mc * rx * rz + ss * ry;
    R[3] = mc * rx * ry + ss * rz; R[4] = cc + mc * ry * ry;       R[5] = mc * ry * rz - ss * rx;
    R[6] = mc * rx * rz - ss * ry; R[7] = mc * ry * rz + ss * rx;  R[8] = cc + mc * rz * rz;
#pragma unroll
    for (int i = 0; i < 9; ++i) Rm[t][i] = R[i];
    if (t >= 1) {
#pragma unroll
      for (int i = 0; i < 9; ++i)
        pf[(size_t)b * NP + (t - 1) * 9 + i] =
            R[i] - ((i == 0 || i == 4 || i == 8) ? 1.f : 0.f);
    }
  }
  __syncthreads();
  if (t == 0) {
#pragma unroll
    for (int r = 0; r < 3; ++r) {
      G[0][r * 4 + 0] = Rm[0][r * 3 + 0];
      G[0][r * 4 + 1] = Rm[0][r * 3 + 1];
      G[0][r * 4 + 2] = Rm[0][r * 3 + 2];
      G[0][r * 4 + 3] = Jl[0][r];
    }
    for (int i = 1; i < NJ; ++i) {
      const int p = parents[i];   // p < i always
      const float tx = Jl[i][0] - Jl[p][0];
      const float ty = Jl[i][1] - Jl[p][1];
      const float tz = Jl[i][2] - Jl[p][2];
#pragma unroll
      for (int r = 0; r < 3; ++r) {
        const float a0 = G[p][r * 4 + 0], a1 = G[p][r * 4 + 1], a2 = G[p][r * 4 + 2];
        G[i][r * 4 + 0] = a0 * Rm[i][0] + a1 * Rm[i][3] + a2 * Rm[i][6];
        G[i][r * 4 + 1] = a0 * Rm[i][1] + a1 * Rm[i][4] + a2 * Rm[i][7];
        G[i][r * 4 + 2] = a0 * Rm[i][2] + a1 * Rm[i][5] + a2 * Rm[i][8];
        G[i][r * 4 + 3] = a0 * tx + a1 * ty + a2 * tz + G[p][r * 4 + 3];
      }
    }
  }
  __syncthreads();
  if (t < NJ) {
    const float jx = Jl[t][0], jy = Jl[t][1], jz = Jl[t][2];
    float* Ab = Aout + (size_t)b * (NJ * 12) + t * 12;
#pragma unroll
    for (int r = 0; r < 3; ++r) {
      const float g0 = G[t][r * 4 + 0], g1 = G[t][r * 4 + 1];
      const float g2 = G[t][r * 4 + 2], g3 = G[t][r * 4 + 3];
      Ab[r * 4 + 0] = g0; Ab[r * 4 + 1] = g1; Ab[r * 4 + 2] = g2;
      Ab[r * 4 + 3] = g3 - (g0 * jx + g1 * jy + g2 * jz);
      out_jt[(size_t)b * (NJ * 3) + t * 3 + r] = to_out(g3);  // J_transformed (pre-subtract)
    }
  }
}

// ---------------------------------------------------------------------------
// K2: the heavy fused vertex kernel. One thread = one vertex x BT batches.
//   v_shaped -> v_posed (K=10 + K=207 GEMMs) -> skinning blend -> verts.
// Per-batch operands (shape, pf, A) read via wave-uniform addresses (s_loads).
// grid: (ceil(NV/256), BATCH/BT) x 256 threads
// ---------------------------------------------------------------------------
__global__ void __launch_bounds__(256, 1) k2_verts(
    const float* __restrict__ shape, const float* __restrict__ vtem,
    const float* __restrict__ sdirs, const float* __restrict__ pdirs,
    const float* __restrict__ wgt, const float* __restrict__ pf,
    const float* __restrict__ Aws, outT* __restrict__ out_verts) {
  const int v = blockIdx.x * 256 + threadIdx.x;
  const bool act = v < NV;
  const int vv = act ? v : (NV - 1);
  const int b0 = blockIdx.y * BT;

  float acc[BT][3];
  {
    const float t0 = vtem[vv * 3 + 0], t1 = vtem[vv * 3 + 1], t2 = vtem[vv * 3 + 2];
#pragma unroll
    for (int bt = 0; bt < BT; ++bt) { acc[bt][0] = t0; acc[bt][1] = t1; acc[bt][2] = t2; }
  }
#pragma unroll
  for (int k = 0; k < 10; ++k) {
    const float d0 = sdirs[(size_t)k * V3 + vv * 3 + 0];
    const float d1 = sdirs[(size_t)k * V3 + vv * 3 + 1];
    const float d2 = sdirs[(size_t)k * V3 + vv * 3 + 2];
#pragma unroll
    for (int bt = 0; bt < BT; ++bt) {
      const float f = shape[(b0 + bt) * 10 + k];  // uniform -> scalar load
      acc[bt][0] += f * d0; acc[bt][1] += f * d1; acc[bt][2] += f * d2;
    }
  }
  for (int p = 0; p < NP; ++p) {
    const float d0 = pdirs[(size_t)p * V3 + vv * 3 + 0];
    const float d1 = pdirs[(size_t)p * V3 + vv * 3 + 1];
    const float d2 = pdirs[(size_t)p * V3 + vv * 3 + 2];
#pragma unroll
    for (int bt = 0; bt < BT; ++bt) {
      const float f = pf[(size_t)(b0 + bt) * NP + p];  // uniform -> scalar load
      acc[bt][0] += f * d0; acc[bt][1] += f * d1; acc[bt][2] += f * d2;
    }
  }
  float w[NJ];
#pragma unroll
  for (int j = 0; j < NJ; ++j) w[j] = wgt[vv * NJ + j];
#pragma unroll
  for (int bt = 0; bt < BT; ++bt) {
    const float* Ab = Aws + (size_t)(b0 + bt) * (NJ * 12);
    float T[12];
#pragma unroll
    for (int k = 0; k < 12; ++k) T[k] = 0.f;
    for (int j = 0; j < NJ; ++j) {
#pragma unroll
      for (int k = 0; k < 12; ++k) T[k] += w[j] * Ab[j * 12 + k];  // Ab uniform -> scalar
    }
    const float x = acc[bt][0], y = acc[bt][1], z = acc[bt][2];
    const float ox = T[0] * x + T[1] * y + T[2]  * z + T[3];
    const float oy = T[4] * x + T[5] * y + T[6]  * z + T[7];
    const float oz = T[8] * x + T[9] * y + T[10] * z + T[11];
    if (act) {
      const size_t o = ((size_t)(b0 + bt) * NV + v) * 3;
      out_verts[o + 0] = to_out(ox);
      out_verts[o + 1] = to_out(oy);
      out_verts[o + 2] = to_out(oz);
    }
  }
}

// ---------------------------------------------------------------------------
// K3: joints[b,r,c] = sum_v verts[b,v,c] * joint_regressor[v,r]
// grid: BATCH blocks, 256 threads (deterministic block reduction, no atomics)
// ---------------------------------------------------------------------------
__global__ void k3_joints(const outT* __restrict__ verts,
                          const float* __restrict__ jr2,
                          outT* __restrict__ out_joints) {
  const int b = blockIdx.x;
  float a[NR * 3];
#pragma unroll
  for (int q = 0; q < NR * 3; ++q) a[q] = 0.f;
  for (int v = threadIdx.x; v < NV; v += 256) {
    const size_t o = (size_t)b * V3 + (size_t)v * 3;
    const float x = from_out(verts[o + 0]);
    const float y = from_out(verts[o + 1]);
    const float z = from_out(verts[o + 2]);
#pragma unroll
    for (int r = 0; r < NR; ++r) {
      const float w = jr2[v * NR + r];
      a[r * 3 + 0] += w * x; a[r * 3 + 1] += w * y; a[r * 3 + 2] += w * z;
    }
  }
  __shared__ float red[4][NR * 3];
  const int lane = threadIdx.x & 63, wv = threadIdx.x >> 6;
#pragma unroll
  for (int q = 0; q < NR * 3; ++q) {
    float x = a[q];
#pragma unroll
    for (int off = 32; off >= 1; off >>= 1) x += __shfl_down(x, off);
    if (lane == 0) red[wv][q] = x;
  }
  __syncthreads();
  if (threadIdx.x < NR * 3) {
    const float s = red[0][threadIdx.x] + red[1][threadIdx.x] +
                    red[2][threadIdx.x] + red[3][threadIdx.x];
    out_joints[(size_t)b * (NR * 3) + threadIdx.x] = to_out(s);
  }
}

// ---------------------------------------------------------------------------
extern "C" void kernel_launch(void* const* d_in, const int* in_sizes, int n_in,
                              void* d_out, int out_size, void* d_ws, size_t ws_size,
                              hipStream_t stream) {
  const float* shape = (const float*)d_in[0];   // (B,10)
  const float* pose  = (const float*)d_in[1];   // (B,72)
  const float* vtem  = (const float*)d_in[2];   // (V,3)
  const float* sdirs = (const float*)d_in[3];   // (10, V*3)
  const float* jreg  = (const float*)d_in[4];   // (V,24)
  const float* pdirs = (const float*)d_in[5];   // (207, V*3)
  const float* wgt   = (const float*)d_in[6];   // (V,24)
  const float* jr2   = (const float*)d_in[7];   // (V,19)
  const int*   par   = (const int*)d_in[8];     // (24,)

  float* ws  = (float*)d_ws;
  float* SDJ = ws;                         // 720
  float* VTJ = ws + 720;                   // 72
  float* pf  = ws + 1024;                  // B*207
  float* Aws = ws + 1024 + BATCH * NP;     // B*288

  outT* out        = (outT*)d_out;
  outT* out_verts  = out;                                   // B*V*3
  outT* out_joints = out + (size_t)BATCH * NV * 3;          // B*19*3
  outT* out_jt     = out_joints + (size_t)BATCH * NR * 3;   // B*24*3

  k0_precompute<<<dim3(72), dim3(256), 0, stream>>>(sdirs, vtem, jreg, SDJ, VTJ);
  k1_chain<<<dim3(BATCH), dim3(128), 0, stream>>>(shape, pose, par, SDJ, VTJ, pf, Aws, out_jt);
  k2_verts<<<dim3((NV + 255) / 256, BATCH / BT), dim3(256), 0, stream>>>(
      shape, vtem, sdirs, pdirs, wgt, pf, Aws, out_verts);
  k3_joints<<<dim3(BATCH), dim3(256), 0, stream>>>(out_verts, jr2, out_joints);
}

// Round 3
// 331.790 us; speedup vs baseline: 1.6800x; 1.6800x over previous
//
#include <hip/hip_runtime.h>
#include <hip/hip_bf16.h>
#include <math.h>

static constexpr int BATCH = 1024;
static constexpr int NV = 6890;
static constexpr int NJ = 24;     // joints
static constexpr int NP = 207;    // pose features
static constexpr int NR = 19;     // regressed joints
static constexpr int V3 = NV * 3;           // 20670
static constexpr int NTILES = (V3 + 15) / 16;   // 1292 n-tiles of 16
static constexpr int KK = 7;                // 7 k-steps of 32 (207 -> 224 padded)
static constexpr int BTILES = BATCH / 16;   // 64 batch tiles of 16

typedef __attribute__((ext_vector_type(8))) short bf16x8;
typedef __attribute__((ext_vector_type(4))) float f32x4;

__device__ __forceinline__ short f2bf(float x) {
  __hip_bfloat16 h = __float2bfloat16(x);
  return __builtin_bit_cast(short, h);
}

// ---------------------------------------------------------------------------
// K0: batch-independent: SDJ[k][jc] = sum_v shapedirs[k,v3] * Jreg[v,j],
//     VTJ[jc] = sum_v v_template * Jreg.   grid 72 x 256
// ---------------------------------------------------------------------------
__global__ void k0_precompute(const float* __restrict__ sdirs,
                              const float* __restrict__ vtem,
                              const float* __restrict__ jreg,
                              float* __restrict__ SDJ,
                              float* __restrict__ VTJ) {
  const int jc = blockIdx.x;
  const int j = jc / 3, c = jc % 3;
  float acc[11];
#pragma unroll
  for (int k = 0; k < 11; ++k) acc[k] = 0.f;
  for (int v = threadIdx.x; v < NV; v += 256) {
    const float w = jreg[v * NJ + j];
    acc[10] += vtem[v * 3 + c] * w;
#pragma unroll
    for (int k = 0; k < 10; ++k) acc[k] += sdirs[(size_t)k * V3 + v * 3 + c] * w;
  }
  __shared__ float red[4][11];
  const int lane = threadIdx.x & 63, wv = threadIdx.x >> 6;
#pragma unroll
  for (int k = 0; k < 11; ++k) {
    float x = acc[k];
#pragma unroll
    for (int off = 32; off >= 1; off >>= 1) x += __shfl_down(x, off);
    if (lane == 0) red[wv][k] = x;
  }
  __syncthreads();
  if (threadIdx.x == 0) {
#pragma unroll
    for (int k = 0; k < 11; ++k) {
      const float s = red[0][k] + red[1][k] + red[2][k] + red[3][k];
      if (k < 10) SDJ[k * 72 + jc] = s;
      else        VTJ[jc] = s;
    }
  }
}

// ---------------------------------------------------------------------------
// K1: per batch: Jloc, Rodrigues, pose_feature (fp32), kinematic chain, A,
//     J_transformed output.  grid BATCH x 128
// ---------------------------------------------------------------------------
__global__ void k1_chain(const float* __restrict__ shape,
                         const float* __restrict__ pose,
                         const int* __restrict__ parents,
                         const float* __restrict__ SDJ,
                         const float* __restrict__ VTJ,
                         float* __restrict__ pf,    // [B][207]
                         float* __restrict__ Aout,  // [B][24][12]
                         float* __restrict__ out_jt)// [B][24][3]
{
  const int b = blockIdx.x;
  const int t = threadIdx.x;
  __shared__ float sh[10];
  __shared__ float Jl[NJ][3];
  __shared__ float Rm[NJ][9];
  __shared__ float G[NJ][12];
  if (t < 10) sh[t] = shape[b * 10 + t];
  __syncthreads();
  if (t < 72) {
    float s = VTJ[t];
#pragma unroll
    for (int k = 0; k < 10; ++k) s += sh[k] * SDJ[k * 72 + t];
    Jl[t / 3][t % 3] = s;
  }
  if (t < NJ) {
    const float px = pose[b * 72 + t * 3 + 0];
    const float py = pose[b * 72 + t * 3 + 1];
    const float pz = pose[b * 72 + t * 3 + 2];
    const float ax = px + 1e-8f, ay = py + 1e-8f, az = pz + 1e-8f;
    const float ang = sqrtf(ax * ax + ay * ay + az * az);
    const float inv = 1.f / ang;
    const float rx = px * inv, ry = py * inv, rz = pz * inv;
    const float cc = cosf(ang), ss = sinf(ang), mc = 1.f - cc;
    float R[9];
    R[0] = cc + mc * rx * rx;      R[1] = mc * rx * ry - ss * rz;  R[2] = mc * rx * rz + ss * ry;
    R[3] = mc * rx * ry + ss * rz; R[4] = cc + mc * ry * ry;       R[5] = mc * ry * rz - ss * rx;
    R[6] = mc * rx * rz - ss * ry; R[7] = mc * ry * rz + ss * rx;  R[8] = cc + mc * rz * rz;
#pragma unroll
    for (int i = 0; i < 9; ++i) Rm[t][i] = R[i];
    if (t >= 1) {
#pragma unroll
      for (int i = 0; i < 9; ++i)
        pf[(size_t)b * NP + (t - 1) * 9 + i] =
            R[i] - ((i == 0 || i == 4 || i == 8) ? 1.f : 0.f);
    }
  }
  __syncthreads();
  if (t == 0) {
#pragma unroll
    for (int r = 0; r < 3; ++r) {
      G[0][r * 4 + 0] = Rm[0][r * 3 + 0];
      G[0][r * 4 + 1] = Rm[0][r * 3 + 1];
      G[0][r * 4 + 2] = Rm[0][r * 3 + 2];
      G[0][r * 4 + 3] = Jl[0][r];
    }
    for (int i = 1; i < NJ; ++i) {
      const int p = parents[i];
      const float tx = Jl[i][0] - Jl[p][0];
      const float ty = Jl[i][1] - Jl[p][1];
      const float tz = Jl[i][2] - Jl[p][2];
#pragma unroll
      for (int r = 0; r < 3; ++r) {
        const float a0 = G[p][r * 4 + 0], a1 = G[p][r * 4 + 1], a2 = G[p][r * 4 + 2];
        G[i][r * 4 + 0] = a0 * Rm[i][0] + a1 * Rm[i][3] + a2 * Rm[i][6];
        G[i][r * 4 + 1] = a0 * Rm[i][1] + a1 * Rm[i][4] + a2 * Rm[i][7];
        G[i][r * 4 + 2] = a0 * Rm[i][2] + a1 * Rm[i][5] + a2 * Rm[i][8];
        G[i][r * 4 + 3] = a0 * tx + a1 * ty + a2 * tz + G[p][r * 4 + 3];
      }
    }
  }
  __syncthreads();
  if (t < NJ) {
    const float jx = Jl[t][0], jy = Jl[t][1], jz = Jl[t][2];
    float* Ab = Aout + (size_t)b * (NJ * 12) + t * 12;
#pragma unroll
    for (int r = 0; r < 3; ++r) {
      const float g0 = G[t][r * 4 + 0], g1 = G[t][r * 4 + 1];
      const float g2 = G[t][r * 4 + 2], g3 = G[t][r * 4 + 3];
      Ab[r * 4 + 0] = g0; Ab[r * 4 + 1] = g1; Ab[r * 4 + 2] = g2;
      Ab[r * 4 + 3] = g3 - (g0 * jx + g1 * jy + g2 * jz);
      out_jt[(size_t)b * (NJ * 3) + t * 3 + r] = g3;
    }
  }
}

// ---------------------------------------------------------------------------
// Pack posedirs (fp32 [207][20670]) -> bf16 MFMA B-frags:
//   Bp[nt][kk][lane][j] = pdirs[kk*32 + (lane>>4)*8 + j][nt*16 + (lane&15)]
// grid NTILES*KK x 64. Same (lane_hi,j)->k mapping used in the A pack, so the
// contraction is correct for any HW k-slot permutation.
// ---------------------------------------------------------------------------
__global__ void k_packB(const float* __restrict__ pdirs, short* __restrict__ Bp) {
  const int blk = blockIdx.x;
  const int nt = blk / KK, kk = blk % KK;
  const int lane = threadIdx.x;
  const int n = nt * 16 + (lane & 15);
  const int k0 = kk * 32 + (lane >> 4) * 8;
  short o[8];
#pragma unroll
  for (int j = 0; j < 8; ++j) {
    const int k = k0 + j;
    o[j] = f2bf((k < NP && n < V3) ? pdirs[(size_t)k * V3 + n] : 0.f);
  }
  *(bf16x8*)(Bp + ((size_t)blk * 64 + lane) * 8) = *(const bf16x8*)o;
}

// Pack pf (fp32 [B][207]) -> bf16 MFMA A-frags, same k mapping.
// grid BTILES*KK x 64
__global__ void k_packA(const float* __restrict__ pf, short* __restrict__ Ap) {
  const int blk = blockIdx.x;
  const int bt = blk / KK, kk = blk % KK;
  const int lane = threadIdx.x;
  const int b = bt * 16 + (lane & 15);
  const int k0 = kk * 32 + (lane >> 4) * 8;
  short o[8];
#pragma unroll
  for (int j = 0; j < 8; ++j) {
    const int k = k0 + j;
    o[j] = f2bf(k < NP ? pf[(size_t)b * NP + k] : 0.f);
  }
  *(bf16x8*)(Ap + ((size_t)blk * 64 + lane) * 8) = *(const bf16x8*)o;
}

// ---------------------------------------------------------------------------
// K2a: MFMA pose GEMM: C[b][n] = pf[b][:207] @ pdirs[:207][n], written fp32
// straight into the d_out verts region. Each wave owns 64 batches (4 b-tiles,
// A-frags held in VGPRs) and streams n-tiles.  grid (48, 16) x 256
// ---------------------------------------------------------------------------
__global__ void __launch_bounds__(256) k2a_mfma(const short* __restrict__ Ap,
                                                const short* __restrict__ Bp,
                                                float* __restrict__ Cout) {
  const int w = threadIdx.x >> 6, lane = threadIdx.x & 63;
  const int by = blockIdx.y;                 // 0..15 -> 64 batches
  const bf16x8* Av = (const bf16x8*)Ap;
  const bf16x8* Bv = (const bf16x8*)Bp;

  bf16x8 a[4][KK];
#pragma unroll
  for (int i = 0; i < 4; ++i) {
    const int btg = by * 4 + i;
#pragma unroll
    for (int kk = 0; kk < KK; ++kk) a[i][kk] = Av[(size_t)(btg * KK + kk) * 64 + lane];
  }
  const int row0 = (lane >> 4) * 4;
  const int colc = lane & 15;

  for (int nt = blockIdx.x * 4 + w; nt < NTILES; nt += gridDim.x * 4) {
    f32x4 acc0 = {0.f, 0.f, 0.f, 0.f};
    f32x4 acc1 = acc0, acc2 = acc0, acc3 = acc0;
#pragma unroll
    for (int kk = 0; kk < KK; ++kk) {
      const bf16x8 bfrag = Bv[(size_t)(nt * KK + kk) * 64 + lane];
      acc0 = __builtin_amdgcn_mfma_f32_16x16x32_bf16(a[0][kk], bfrag, acc0, 0, 0, 0);
      acc1 = __builtin_amdgcn_mfma_f32_16x16x32_bf16(a[1][kk], bfrag, acc1, 0, 0, 0);
      acc2 = __builtin_amdgcn_mfma_f32_16x16x32_bf16(a[2][kk], bfrag, acc2, 0, 0, 0);
      acc3 = __builtin_amdgcn_mfma_f32_16x16x32_bf16(a[3][kk], bfrag, acc3, 0, 0, 0);
    }
    const int n = nt * 16 + colc;
    if (n < V3) {
      const int bbase = by * 64 + row0;
#pragma unroll
      for (int r = 0; r < 4; ++r) {
        Cout[(size_t)(bbase + 0 * 16 + r) * V3 + n] = acc0[r];
        Cout[(size_t)(bbase + 1 * 16 + r) * V3 + n] = acc1[r];
        Cout[(size_t)(bbase + 2 * 16 + r) * V3 + n] = acc2[r];
        Cout[(size_t)(bbase + 3 * 16 + r) * V3 + n] = acc3[r];
      }
    }
  }
}

// ---------------------------------------------------------------------------
// K2b: in-place finish: verts = LBS( v_template + shapeblend + Cpose ).
// One thread = one vertex x 4 batches. A read as contiguous wide scalar
// loads per (batch,joint); weights as contiguous per-lane vector loads.
// grid (27, 256) x 256
// ---------------------------------------------------------------------------
__global__ void __launch_bounds__(256) k2b_skin(const float* __restrict__ shape,
                                                const float* __restrict__ vtem,
                                                const float* __restrict__ sdirs,
                                                const float* __restrict__ wgt,
                                                const float* __restrict__ Aws,
                                                float* __restrict__ verts) {
  const int v = blockIdx.x * 256 + threadIdx.x;
  if (v >= NV) return;              // no barriers below -> safe
  const int b0 = blockIdx.y * 4;

  const float t0 = vtem[v * 3 + 0], t1 = vtem[v * 3 + 1], t2 = vtem[v * 3 + 2];
  float vph[4][3];
#pragma unroll
  for (int bt = 0; bt < 4; ++bt) {
    const size_t o = (size_t)(b0 + bt) * V3 + (size_t)v * 3;
    vph[bt][0] = verts[o + 0] + t0;
    vph[bt][1] = verts[o + 1] + t1;
    vph[bt][2] = verts[o + 2] + t2;
  }
#pragma unroll
  for (int k = 0; k < 10; ++k) {
    const float d0 = sdirs[(size_t)k * V3 + v * 3 + 0];
    const float d1 = sdirs[(size_t)k * V3 + v * 3 + 1];
    const float d2 = sdirs[(size_t)k * V3 + v * 3 + 2];
#pragma unroll
    for (int bt = 0; bt < 4; ++bt) {
      const float s = shape[(b0 + bt) * 10 + k];   // uniform scalar
      vph[bt][0] += s * d0; vph[bt][1] += s * d1; vph[bt][2] += s * d2;
    }
  }
  float w[NJ];
#pragma unroll
  for (int j = 0; j < NJ; ++j) w[j] = wgt[v * NJ + j];  // 96B contiguous

  float T[4][12];
#pragma unroll
  for (int bt = 0; bt < 4; ++bt)
#pragma unroll
    for (int k = 0; k < 12; ++k) T[bt][k] = 0.f;

  for (int j = 0; j < NJ; ++j) {
    const float wj = w[j];
#pragma unroll
    for (int bt = 0; bt < 4; ++bt) {
      const float* As = Aws + (size_t)(b0 + bt) * (NJ * 12) + j * 12;  // uniform, contiguous 48B
#pragma unroll
      for (int k = 0; k < 12; ++k) T[bt][k] += wj * As[k];
    }
  }
#pragma unroll
  for (int bt = 0; bt < 4; ++bt) {
    const float x = vph[bt][0], y = vph[bt][1], z = vph[bt][2];
    const size_t o = (size_t)(b0 + bt) * V3 + (size_t)v * 3;
    verts[o + 0] = T[bt][0] * x + T[bt][1] * y + T[bt][2]  * z + T[bt][3];
    verts[o + 1] = T[bt][4] * x + T[bt][5] * y + T[bt][6]  * z + T[bt][7];
    verts[o + 2] = T[bt][8] * x + T[bt][9] * y + T[bt][10] * z + T[bt][11];
  }
}

// ---------------------------------------------------------------------------
// K3: joints[b,r,c] = sum_v verts[b,v,c] * joint_regressor[v,r]
// grid BATCH x 256
// ---------------------------------------------------------------------------
__global__ void k3_joints(const float* __restrict__ verts,
                          const float* __restrict__ jr2,
                          float* __restrict__ out_joints) {
  const int b = blockIdx.x;
  float a[NR * 3];
#pragma unroll
  for (int q = 0; q < NR * 3; ++q) a[q] = 0.f;
  for (int v = threadIdx.x; v < NV; v += 256) {
    const size_t o = (size_t)b * V3 + (size_t)v * 3;
    const float x = verts[o + 0];
    const float y = verts[o + 1];
    const float z = verts[o + 2];
#pragma unroll
    for (int r = 0; r < NR; ++r) {
      const float w = jr2[v * NR + r];
      a[r * 3 + 0] += w * x; a[r * 3 + 1] += w * y; a[r * 3 + 2] += w * z;
    }
  }
  __shared__ float red[4][NR * 3];
  const int lane = threadIdx.x & 63, wv = threadIdx.x >> 6;
#pragma unroll
  for (int q = 0; q < NR * 3; ++q) {
    float x = a[q];
#pragma unroll
    for (int off = 32; off >= 1; off >>= 1) x += __shfl_down(x, off);
    if (lane == 0) red[wv][q] = x;
  }
  __syncthreads();
  if (threadIdx.x < NR * 3) {
    const float s = red[0][threadIdx.x] + red[1][threadIdx.x] +
                    red[2][threadIdx.x] + red[3][threadIdx.x];
    out_joints[(size_t)b * (NR * 3) + threadIdx.x] = s;
  }
}

// ---------------------------------------------------------------------------
extern "C" void kernel_launch(void* const* d_in, const int* in_sizes, int n_in,
                              void* d_out, int out_size, void* d_ws, size_t ws_size,
                              hipStream_t stream) {
  const float* shape = (const float*)d_in[0];
  const float* pose  = (const float*)d_in[1];
  const float* vtem  = (const float*)d_in[2];
  const float* sdirs = (const float*)d_in[3];
  const float* jreg  = (const float*)d_in[4];
  const float* pdirs = (const float*)d_in[5];
  const float* wgt   = (const float*)d_in[6];
  const float* jr2   = (const float*)d_in[7];
  const int*   par   = (const int*)d_in[8];

  float* ws  = (float*)d_ws;
  float* SDJ = ws;                              // 720
  float* VTJ = ws + 720;                        // 72
  float* pf  = ws + 1024;                       // B*207     fp32
  float* Aws = pf + BATCH * NP;                 // B*288     fp32
  short* Ap  = (short*)(Aws + BATCH * NJ * 12); // BTILES*KK*64*8 bf16
  short* Bp  = Ap + (size_t)BTILES * KK * 64 * 8; // NTILES*KK*64*8 bf16

  float* out        = (float*)d_out;
  float* out_verts  = out;                                  // B*V*3
  float* out_joints = out + (size_t)BATCH * NV * 3;         // B*19*3
  float* out_jt     = out_joints + (size_t)BATCH * NR * 3;  // B*24*3

  k_packB<<<dim3(NTILES * KK), dim3(64), 0, stream>>>(pdirs, Bp);
  k0_precompute<<<dim3(72), dim3(256), 0, stream>>>(sdirs, vtem, jreg, SDJ, VTJ);
  k1_chain<<<dim3(BATCH), dim3(128), 0, stream>>>(shape, pose, par, SDJ, VTJ, pf, Aws, out_jt);
  k_packA<<<dim3(BTILES * KK), dim3(64), 0, stream>>>(pf, Ap);
  k2a_mfma<<<dim3(48, 16), dim3(256), 0, stream>>>(Ap, Bp, out_verts);
  k2b_skin<<<dim3((NV + 255) / 256, BATCH / 4), dim3(256), 0, stream>>>(
      shape, vtem, sdirs, wgt, Aws, out_verts);
  k3_joints<<<dim3(BATCH), dim3(256), 0, stream>>>(out_verts, jr2, out_joints);
}

// Round 4
// 259.830 us; speedup vs baseline: 2.1453x; 1.2769x over previous
//
#include <hip/hip_runtime.h>
#include <hip/hip_bf16.h>
#include <math.h>

static constexpr int BATCH = 1024;
static constexpr int NV = 6890;
static constexpr int NJ = 24;     // joints
static constexpr int NP = 207;    // pose features
static constexpr int NR = 19;     // regressed joints
static constexpr int V3 = NV * 3;           // 20670
static constexpr int NTILES = (V3 + 15) / 16;   // 1292 n-tiles of 16
static constexpr int KK = 7;                // 7 k-steps of 32 (207 -> 224 padded)
static constexpr int BTILES = BATCH / 16;   // 64 batch tiles of 16

typedef __attribute__((ext_vector_type(8))) short bf16x8;
typedef __attribute__((ext_vector_type(4))) float f32x4;

__device__ __forceinline__ short f2bf(float x) {
  __hip_bfloat16 h = __float2bfloat16(x);
  return __builtin_bit_cast(short, h);
}

// ---------------------------------------------------------------------------
// K0: batch-independent: SDJ[k][jc] = sum_v shapedirs[k,v3] * Jreg[v,j],
//     VTJ[jc] = sum_v v_template * Jreg.   grid 72 x 256
// ---------------------------------------------------------------------------
__global__ void k0_precompute(const float* __restrict__ sdirs,
                              const float* __restrict__ vtem,
                              const float* __restrict__ jreg,
                              float* __restrict__ SDJ,
                              float* __restrict__ VTJ) {
  const int jc = blockIdx.x;
  const int j = jc / 3, c = jc % 3;
  float acc[11];
#pragma unroll
  for (int k = 0; k < 11; ++k) acc[k] = 0.f;
  for (int v = threadIdx.x; v < NV; v += 256) {
    const float w = jreg[v * NJ + j];
    acc[10] += vtem[v * 3 + c] * w;
#pragma unroll
    for (int k = 0; k < 10; ++k) acc[k] += sdirs[(size_t)k * V3 + v * 3 + c] * w;
  }
  __shared__ float red[4][11];
  const int lane = threadIdx.x & 63, wv = threadIdx.x >> 6;
#pragma unroll
  for (int k = 0; k < 11; ++k) {
    float x = acc[k];
#pragma unroll
    for (int off = 32; off >= 1; off >>= 1) x += __shfl_down(x, off);
    if (lane == 0) red[wv][k] = x;
  }
  __syncthreads();
  if (threadIdx.x == 0) {
#pragma unroll
    for (int k = 0; k < 11; ++k) {
      const float s = red[0][k] + red[1][k] + red[2][k] + red[3][k];
      if (k < 10) SDJ[k * 72 + jc] = s;
      else        VTJ[jc] = s;
    }
  }
}

// ---------------------------------------------------------------------------
// K1: per batch: Jloc, Rodrigues, pose_feature (fp32), kinematic chain, A,
//     J_transformed output.  grid BATCH x 128
// ---------------------------------------------------------------------------
__global__ void k1_chain(const float* __restrict__ shape,
                         const float* __restrict__ pose,
                         const int* __restrict__ parents,
                         const float* __restrict__ SDJ,
                         const float* __restrict__ VTJ,
                         float* __restrict__ pf,    // [B][207]
                         float* __restrict__ Aout,  // [B][24][12]
                         float* __restrict__ out_jt)// [B][24][3]
{
  const int b = blockIdx.x;
  const int t = threadIdx.x;
  __shared__ float sh[10];
  __shared__ float Jl[NJ][3];
  __shared__ float Rm[NJ][9];
  __shared__ float G[NJ][12];
  if (t < 10) sh[t] = shape[b * 10 + t];
  __syncthreads();
  if (t < 72) {
    float s = VTJ[t];
#pragma unroll
    for (int k = 0; k < 10; ++k) s += sh[k] * SDJ[k * 72 + t];
    Jl[t / 3][t % 3] = s;
  }
  if (t < NJ) {
    const float px = pose[b * 72 + t * 3 + 0];
    const float py = pose[b * 72 + t * 3 + 1];
    const float pz = pose[b * 72 + t * 3 + 2];
    const float ax = px + 1e-8f, ay = py + 1e-8f, az = pz + 1e-8f;
    const float ang = sqrtf(ax * ax + ay * ay + az * az);
    const float inv = 1.f / ang;
    const float rx = px * inv, ry = py * inv, rz = pz * inv;
    const float cc = cosf(ang), ss = sinf(ang), mc = 1.f - cc;
    float R[9];
    R[0] = cc + mc * rx * rx;      R[1] = mc * rx * ry - ss * rz;  R[2] = mc * rx * rz + ss * ry;
    R[3] = mc * rx * ry + ss * rz; R[4] = cc + mc * ry * ry;       R[5] = mc * ry * rz - ss * rx;
    R[6] = mc * rx * rz - ss * ry; R[7] = mc * ry * rz + ss * rx;  R[8] = cc + mc * rz * rz;
#pragma unroll
    for (int i = 0; i < 9; ++i) Rm[t][i] = R[i];
    if (t >= 1) {
#pragma unroll
      for (int i = 0; i < 9; ++i)
        pf[(size_t)b * NP + (t - 1) * 9 + i] =
            R[i] - ((i == 0 || i == 4 || i == 8) ? 1.f : 0.f);
    }
  }
  __syncthreads();
  if (t == 0) {
#pragma unroll
    for (int r = 0; r < 3; ++r) {
      G[0][r * 4 + 0] = Rm[0][r * 3 + 0];
      G[0][r * 4 + 1] = Rm[0][r * 3 + 1];
      G[0][r * 4 + 2] = Rm[0][r * 3 + 2];
      G[0][r * 4 + 3] = Jl[0][r];
    }
    for (int i = 1; i < NJ; ++i) {
      const int p = parents[i];
      const float tx = Jl[i][0] - Jl[p][0];
      const float ty = Jl[i][1] - Jl[p][1];
      const float tz = Jl[i][2] - Jl[p][2];
#pragma unroll
      for (int r = 0; r < 3; ++r) {
        const float a0 = G[p][r * 4 + 0], a1 = G[p][r * 4 + 1], a2 = G[p][r * 4 + 2];
        G[i][r * 4 + 0] = a0 * Rm[i][0] + a1 * Rm[i][3] + a2 * Rm[i][6];
        G[i][r * 4 + 1] = a0 * Rm[i][1] + a1 * Rm[i][4] + a2 * Rm[i][7];
        G[i][r * 4 + 2] = a0 * Rm[i][2] + a1 * Rm[i][5] + a2 * Rm[i][8];
        G[i][r * 4 + 3] = a0 * tx + a1 * ty + a2 * tz + G[p][r * 4 + 3];
      }
    }
  }
  __syncthreads();
  if (t < NJ) {
    const float jx = Jl[t][0], jy = Jl[t][1], jz = Jl[t][2];
    float* Ab = Aout + (size_t)b * (NJ * 12) + t * 12;
#pragma unroll
    for (int r = 0; r < 3; ++r) {
      const float g0 = G[t][r * 4 + 0], g1 = G[t][r * 4 + 1];
      const float g2 = G[t][r * 4 + 2], g3 = G[t][r * 4 + 3];
      Ab[r * 4 + 0] = g0; Ab[r * 4 + 1] = g1; Ab[r * 4 + 2] = g2;
      Ab[r * 4 + 3] = g3 - (g0 * jx + g1 * jy + g2 * jz);
      out_jt[(size_t)b * (NJ * 3) + t * 3 + r] = g3;
    }
  }
}

// ---------------------------------------------------------------------------
// Pack posedirs (fp32 [207][20670]) -> bf16 MFMA B-frags:
//   Bp[nt][kk][lane][j] = pdirs[kk*32 + (lane>>4)*8 + j][nt*16 + (lane&15)]
// grid NTILES*KK x 64
// ---------------------------------------------------------------------------
__global__ void k_packB(const float* __restrict__ pdirs, short* __restrict__ Bp) {
  const int blk = blockIdx.x;
  const int nt = blk / KK, kk = blk % KK;
  const int lane = threadIdx.x;
  const int n = nt * 16 + (lane & 15);
  const int k0 = kk * 32 + (lane >> 4) * 8;
  short o[8];
#pragma unroll
  for (int j = 0; j < 8; ++j) {
    const int k = k0 + j;
    o[j] = f2bf((k < NP && n < V3) ? pdirs[(size_t)k * V3 + n] : 0.f);
  }
  *(bf16x8*)(Bp + ((size_t)blk * 64 + lane) * 8) = *(const bf16x8*)o;
}

// Pack pf (fp32 [B][207]) -> bf16 MFMA A-frags, same k mapping.
// grid BTILES*KK x 64
__global__ void k_packA(const float* __restrict__ pf, short* __restrict__ Ap) {
  const int blk = blockIdx.x;
  const int bt = blk / KK, kk = blk % KK;
  const int lane = threadIdx.x;
  const int b = bt * 16 + (lane & 15);
  const int k0 = kk * 32 + (lane >> 4) * 8;
  short o[8];
#pragma unroll
  for (int j = 0; j < 8; ++j) {
    const int k = k0 + j;
    o[j] = f2bf(k < NP ? pf[(size_t)b * NP + k] : 0.f);
  }
  *(bf16x8*)(Ap + ((size_t)blk * 64 + lane) * 8) = *(const bf16x8*)o;
}

// ---------------------------------------------------------------------------
// K2a: MFMA pose GEMM: C[b][n] = pf[b][:207] @ pdirs[:207][n], fp32 into the
// d_out verts region.  grid (48, 16) x 256
// ---------------------------------------------------------------------------
__global__ void __launch_bounds__(256) k2a_mfma(const short* __restrict__ Ap,
                                                const short* __restrict__ Bp,
                                                float* __restrict__ Cout) {
  const int w = threadIdx.x >> 6, lane = threadIdx.x & 63;
  const int by = blockIdx.y;                 // 0..15 -> 64 batches
  const bf16x8* Av = (const bf16x8*)Ap;
  const bf16x8* Bv = (const bf16x8*)Bp;

  bf16x8 a[4][KK];
#pragma unroll
  for (int i = 0; i < 4; ++i) {
    const int btg = by * 4 + i;
#pragma unroll
    for (int kk = 0; kk < KK; ++kk) a[i][kk] = Av[(size_t)(btg * KK + kk) * 64 + lane];
  }
  const int row0 = (lane >> 4) * 4;
  const int colc = lane & 15;

  for (int nt = blockIdx.x * 4 + w; nt < NTILES; nt += gridDim.x * 4) {
    f32x4 acc0 = {0.f, 0.f, 0.f, 0.f};
    f32x4 acc1 = acc0, acc2 = acc0, acc3 = acc0;
#pragma unroll
    for (int kk = 0; kk < KK; ++kk) {
      const bf16x8 bfrag = Bv[(size_t)(nt * KK + kk) * 64 + lane];
      acc0 = __builtin_amdgcn_mfma_f32_16x16x32_bf16(a[0][kk], bfrag, acc0, 0, 0, 0);
      acc1 = __builtin_amdgcn_mfma_f32_16x16x32_bf16(a[1][kk], bfrag, acc1, 0, 0, 0);
      acc2 = __builtin_amdgcn_mfma_f32_16x16x32_bf16(a[2][kk], bfrag, acc2, 0, 0, 0);
      acc3 = __builtin_amdgcn_mfma_f32_16x16x32_bf16(a[3][kk], bfrag, acc3, 0, 0, 0);
    }
    const int n = nt * 16 + colc;
    if (n < V3) {
      const int bbase = by * 64 + row0;
#pragma unroll
      for (int r = 0; r < 4; ++r) {
        Cout[(size_t)(bbase + 0 * 16 + r) * V3 + n] = acc0[r];
        Cout[(size_t)(bbase + 1 * 16 + r) * V3 + n] = acc1[r];
        Cout[(size_t)(bbase + 2 * 16 + r) * V3 + n] = acc2[r];
        Cout[(size_t)(bbase + 3 * 16 + r) * V3 + n] = acc3[r];
      }
    }
  }
}

// ---------------------------------------------------------------------------
// K2b: in-place finish: verts = LBS( v_template + shapeblend + Cpose ).
// One thread = one vertex x 4 batches. A staged in LDS (4 x 288 floats);
// T-build reads are uniform-address ds_read_b128 broadcasts (conflict-free),
// fully unrolled so loads pipeline ahead of the FMAs.
// grid (27, 256) x 256
// ---------------------------------------------------------------------------
__global__ void __launch_bounds__(256) k2b_skin(const float* __restrict__ shape,
                                                const float* __restrict__ vtem,
                                                const float* __restrict__ sdirs,
                                                const float* __restrict__ wgt,
                                                const float* __restrict__ Aws,
                                                float* __restrict__ verts) {
  __shared__ float Alds[4 * NJ * 12];   // 4 batches x 288 floats = 4.6 KB
  const int b0 = blockIdx.y * 4;
  for (int i = threadIdx.x; i < 4 * NJ * 12; i += 256)
    Alds[i] = Aws[(size_t)b0 * (NJ * 12) + i];
  __syncthreads();

  const int v = blockIdx.x * 256 + threadIdx.x;
  if (v >= NV) return;              // after the only barrier -> safe

  const float t0 = vtem[v * 3 + 0], t1 = vtem[v * 3 + 1], t2 = vtem[v * 3 + 2];
  float vph[4][3];
#pragma unroll
  for (int bt = 0; bt < 4; ++bt) {
    const size_t o = (size_t)(b0 + bt) * V3 + (size_t)v * 3;
    vph[bt][0] = verts[o + 0] + t0;
    vph[bt][1] = verts[o + 1] + t1;
    vph[bt][2] = verts[o + 2] + t2;
  }
#pragma unroll
  for (int k = 0; k < 10; ++k) {
    const float d0 = sdirs[(size_t)k * V3 + v * 3 + 0];
    const float d1 = sdirs[(size_t)k * V3 + v * 3 + 1];
    const float d2 = sdirs[(size_t)k * V3 + v * 3 + 2];
#pragma unroll
    for (int bt = 0; bt < 4; ++bt) {
      const float s = shape[(b0 + bt) * 10 + k];   // uniform scalar
      vph[bt][0] += s * d0; vph[bt][1] += s * d1; vph[bt][2] += s * d2;
    }
  }
  float w[NJ];
#pragma unroll
  for (int j = 0; j < NJ; ++j) w[j] = wgt[v * NJ + j];  // 96B contiguous

  float T[4][12];
#pragma unroll
  for (int bt = 0; bt < 4; ++bt)
#pragma unroll
    for (int k = 0; k < 12; ++k) T[bt][k] = 0.f;

#pragma unroll
  for (int j = 0; j < NJ; ++j) {
    const float wj = w[j];
#pragma unroll
    for (int bt = 0; bt < 4; ++bt) {
      // uniform LDS address -> broadcast ds_read_b128 x3, conflict-free
      const f32x4 a0 = *(const f32x4*)&Alds[bt * (NJ * 12) + j * 12 + 0];
      const f32x4 a1 = *(const f32x4*)&Alds[bt * (NJ * 12) + j * 12 + 4];
      const f32x4 a2 = *(const f32x4*)&Alds[bt * (NJ * 12) + j * 12 + 8];
#pragma unroll
      for (int k = 0; k < 4; ++k) {
        T[bt][k + 0] += wj * a0[k];
        T[bt][k + 4] += wj * a1[k];
        T[bt][k + 8] += wj * a2[k];
      }
    }
  }
#pragma unroll
  for (int bt = 0; bt < 4; ++bt) {
    const float x = vph[bt][0], y = vph[bt][1], z = vph[bt][2];
    const size_t o = (size_t)(b0 + bt) * V3 + (size_t)v * 3;
    verts[o + 0] = T[bt][0] * x + T[bt][1] * y + T[bt][2]  * z + T[bt][3];
    verts[o + 1] = T[bt][4] * x + T[bt][5] * y + T[bt][6]  * z + T[bt][7];
    verts[o + 2] = T[bt][8] * x + T[bt][9] * y + T[bt][10] * z + T[bt][11];
  }
}

// ---------------------------------------------------------------------------
// K3: joints[b,r,c] = sum_v verts[b,v,c] * joint_regressor[v,r]
// grid BATCH x 256
// ---------------------------------------------------------------------------
__global__ void k3_joints(const float* __restrict__ verts,
                          const float* __restrict__ jr2,
                          float* __restrict__ out_joints) {
  const int b = blockIdx.x;
  float a[NR * 3];
#pragma unroll
  for (int q = 0; q < NR * 3; ++q) a[q] = 0.f;
  for (int v = threadIdx.x; v < NV; v += 256) {
    const size_t o = (size_t)b * V3 + (size_t)v * 3;
    const float x = verts[o + 0];
    const float y = verts[o + 1];
    const float z = verts[o + 2];
#pragma unroll
    for (int r = 0; r < NR; ++r) {
      const float w = jr2[v * NR + r];
      a[r * 3 + 0] += w * x; a[r * 3 + 1] += w * y; a[r * 3 + 2] += w * z;
    }
  }
  __shared__ float red[4][NR * 3];
  const int lane = threadIdx.x & 63, wv = threadIdx.x >> 6;
#pragma unroll
  for (int q = 0; q < NR * 3; ++q) {
    float x = a[q];
#pragma unroll
    for (int off = 32; off >= 1; off >>= 1) x += __shfl_down(x, off);
    if (lane == 0) red[wv][q] = x;
  }
  __syncthreads();
  if (threadIdx.x < NR * 3) {
    const float s = red[0][threadIdx.x] + red[1][threadIdx.x] +
                    red[2][threadIdx.x] + red[3][threadIdx.x];
    out_joints[(size_t)b * (NR * 3) + threadIdx.x] = s;
  }
}

// ---------------------------------------------------------------------------
extern "C" void kernel_launch(void* const* d_in, const int* in_sizes, int n_in,
                              void* d_out, int out_size, void* d_ws, size_t ws_size,
                              hipStream_t stream) {
  const float* shape = (const float*)d_in[0];
  const float* pose  = (const float*)d_in[1];
  const float* vtem  = (const float*)d_in[2];
  const float* sdirs = (const float*)d_in[3];
  const float* jreg  = (const float*)d_in[4];
  const float* pdirs = (const float*)d_in[5];
  const float* wgt   = (const float*)d_in[6];
  const float* jr2   = (const float*)d_in[7];
  const int*   par   = (const int*)d_in[8];

  float* ws  = (float*)d_ws;
  float* SDJ = ws;                              // 720
  float* VTJ = ws + 720;                        // 72
  float* pf  = ws + 1024;                       // B*207     fp32
  float* Aws = pf + BATCH * NP;                 // B*288     fp32
  short* Ap  = (short*)(Aws + BATCH * NJ * 12); // BTILES*KK*64*8 bf16
  short* Bp  = Ap + (size_t)BTILES * KK * 64 * 8; // NTILES*KK*64*8 bf16

  float* out        = (float*)d_out;
  float* out_verts  = out;                                  // B*V*3
  float* out_joints = out + (size_t)BATCH * NV * 3;         // B*19*3
  float* out_jt     = out_joints + (size_t)BATCH * NR * 3;  // B*24*3

  k_packB<<<dim3(NTILES * KK), dim3(64), 0, stream>>>(pdirs, Bp);
  k0_precompute<<<dim3(72), dim3(256), 0, stream>>>(sdirs, vtem, jreg, SDJ, VTJ);
  k1_chain<<<dim3(BATCH), dim3(128), 0, stream>>>(shape, pose, par, SDJ, VTJ, pf, Aws, out_jt);
  k_packA<<<dim3(BTILES * KK), dim3(64), 0, stream>>>(pf, Ap);
  k2a_mfma<<<dim3(48, 16), dim3(256), 0, stream>>>(Ap, Bp, out_verts);
  k2b_skin<<<dim3((NV + 255) / 256, BATCH / 4), dim3(256), 0, stream>>>(
      shape, vtem, sdirs, wgt, Aws, out_verts);
  k3_joints<<<dim3(BATCH), dim3(256), 0, stream>>>(out_verts, jr2, out_joints);
}

// Round 7
// 229.499 us; speedup vs baseline: 2.4288x; 1.1322x over previous
//
#include <hip/hip_runtime.h>
#include <hip/hip_bf16.h>
#include <math.h>

static constexpr int BATCH = 1024;
static constexpr int NV = 6890;
static constexpr int NJ = 24;     // joints
static constexpr int NP = 207;    // pose features
static constexpr int NR = 19;     // regressed joints
static constexpr int V3 = NV * 3;               // 20670
static constexpr int KK = 7;                    // 7 k-steps of 32 (207->224)
static constexpr int BTILES = BATCH / 16;       // 64 batch tiles
static constexpr int XBLK = 108;                // v-blocks of 64 verts (6912 >= NV)
static constexpr int NT_PAD = XBLK * 12;        // 1296 padded v3-tiles of 16
static constexpr int TSTR = 196;                // Cls row stride (dwords), 16B-aligned

typedef __attribute__((ext_vector_type(8))) short bf16x8;
typedef __attribute__((ext_vector_type(4))) float f32x4;

__device__ __forceinline__ short f2bf(float x) {
  __hip_bfloat16 h = __float2bfloat16(x);
  return __builtin_bit_cast(short, h);
}

// ---------------------------------------------------------------------------
// K0: batch-independent: SDJ[k][jc] = sum_v shapedirs[k,v3]*Jreg[v,j],
//     VTJ[jc] = sum_v v_template*Jreg.   grid 72 x 256
// ---------------------------------------------------------------------------
__global__ void k0_precompute(const float* __restrict__ sdirs,
                              const float* __restrict__ vtem,
                              const float* __restrict__ jreg,
                              float* __restrict__ SDJ,
                              float* __restrict__ VTJ) {
  const int jc = blockIdx.x;
  const int j = jc / 3, c = jc % 3;
  float acc[11];
#pragma unroll
  for (int k = 0; k < 11; ++k) acc[k] = 0.f;
  for (int v = threadIdx.x; v < NV; v += 256) {
    const float w = jreg[v * NJ + j];
    acc[10] += vtem[v * 3 + c] * w;
#pragma unroll
    for (int k = 0; k < 10; ++k) acc[k] += sdirs[(size_t)k * V3 + v * 3 + c] * w;
  }
  __shared__ float red[4][11];
  const int lane = threadIdx.x & 63, wv = threadIdx.x >> 6;
#pragma unroll
  for (int k = 0; k < 11; ++k) {
    float x = acc[k];
#pragma unroll
    for (int off = 32; off >= 1; off >>= 1) x += __shfl_down(x, off);
    if (lane == 0) red[wv][k] = x;
  }
  __syncthreads();
  if (threadIdx.x == 0) {
#pragma unroll
    for (int k = 0; k < 11; ++k) {
      const float s = red[0][k] + red[1][k] + red[2][k] + red[3][k];
      if (k < 10) SDJ[k * 72 + jc] = s;
      else        VTJ[jc] = s;
    }
  }
}

// ---------------------------------------------------------------------------
// K1: per batch: Jloc, Rodrigues, kinematic chain, J_out.
//   - Ap (bf16 MFMA A-frags of pose_feature) emitted directly:
//     Ap[bt][kk][lane][j] = bf16(pf[b][kk*32 + (lane>>4)*8 + j]), b=bt*16+(lane&15)
//   - Aws fp32 [B][24][12] (proven round-4 path) for the fp32 skinning stage
// grid BATCH x 128
// ---------------------------------------------------------------------------
__global__ void k1_chain(const float* __restrict__ shape,
                         const float* __restrict__ pose,
                         const int* __restrict__ parents,
                         const float* __restrict__ SDJ,
                         const float* __restrict__ VTJ,
                         short* __restrict__ Ap,
                         float* __restrict__ Aws,   // [B][24][12]
                         float* __restrict__ out_jt)// [B][24][3]
{
  const int b = blockIdx.x;
  const int t = threadIdx.x;
  const int bt = b >> 4, b16 = b & 15;
  __shared__ float sh[10];
  __shared__ float Jl[NJ][3];
  __shared__ float Rm[NJ][9];
  __shared__ float G[NJ][12];
  if (t < 10) sh[t] = shape[b * 10 + t];
  __syncthreads();
  if (t < 72) {
    float s = VTJ[t];
#pragma unroll
    for (int k = 0; k < 10; ++k) s += sh[k] * SDJ[k * 72 + t];
    Jl[t / 3][t % 3] = s;
  }
  if (t < NJ) {
    const float px = pose[b * 72 + t * 3 + 0];
    const float py = pose[b * 72 + t * 3 + 1];
    const float pz = pose[b * 72 + t * 3 + 2];
    const float ax = px + 1e-8f, ay = py + 1e-8f, az = pz + 1e-8f;
    const float ang = sqrtf(ax * ax + ay * ay + az * az);
    const float inv = 1.f / ang;
    const float rx = px * inv, ry = py * inv, rz = pz * inv;
    const float cc = cosf(ang), ss = sinf(ang), mc = 1.f - cc;
    float R[9];
    R[0] = cc + mc * rx * rx;      R[1] = mc * rx * ry - ss * rz;  R[2] = mc * rx * rz + ss * ry;
    R[3] = mc * rx * ry + ss * rz; R[4] = cc + mc * ry * ry;       R[5] = mc * ry * rz - ss * rx;
    R[6] = mc * rx * rz - ss * ry; R[7] = mc * ry * rz + ss * rx;  R[8] = cc + mc * rz * rz;
#pragma unroll
    for (int i = 0; i < 9; ++i) Rm[t][i] = R[i];
    if (t >= 1) {
      // pose_feature -> Ap fragments (bf16), k = (t-1)*9 + i
#pragma unroll
      for (int i = 0; i < 9; ++i) {
        const float val = R[i] - ((i == 0 || i == 4 || i == 8) ? 1.f : 0.f);
        const int k = (t - 1) * 9 + i;
        const int kk = k >> 5, g = (k & 31) >> 3, jj = k & 7;
        Ap[(((size_t)bt * KK + kk) * 64 + b16 + 16 * g) * 8 + jj] = f2bf(val);
      }
    }
  }
  // Ap zero-padding for k in [207,224): threads 24..40 handle one k each
  if (t >= 24 && t < 41) {
    const int k = t + 183;            // 207..223
    const int kk = k >> 5, g = (k & 31) >> 3, jj = k & 7;
    Ap[(((size_t)bt * KK + kk) * 64 + b16 + 16 * g) * 8 + jj] = 0;
  }
  __syncthreads();
  if (t == 0) {
#pragma unroll
    for (int r = 0; r < 3; ++r) {
      G[0][r * 4 + 0] = Rm[0][r * 3 + 0];
      G[0][r * 4 + 1] = Rm[0][r * 3 + 1];
      G[0][r * 4 + 2] = Rm[0][r * 3 + 2];
      G[0][r * 4 + 3] = Jl[0][r];
    }
    for (int i = 1; i < NJ; ++i) {
      const int p = parents[i];
      const float tx = Jl[i][0] - Jl[p][0];
      const float ty = Jl[i][1] - Jl[p][1];
      const float tz = Jl[i][2] - Jl[p][2];
#pragma unroll
      for (int r = 0; r < 3; ++r) {
        const float a0 = G[p][r * 4 + 0], a1 = G[p][r * 4 + 1], a2 = G[p][r * 4 + 2];
        G[i][r * 4 + 0] = a0 * Rm[i][0] + a1 * Rm[i][3] + a2 * Rm[i][6];
        G[i][r * 4 + 1] = a0 * Rm[i][1] + a1 * Rm[i][4] + a2 * Rm[i][7];
        G[i][r * 4 + 2] = a0 * Rm[i][2] + a1 * Rm[i][5] + a2 * Rm[i][8];
        G[i][r * 4 + 3] = a0 * tx + a1 * ty + a2 * tz + G[p][r * 4 + 3];
      }
    }
  }
  __syncthreads();
  if (t < NJ) {
    const float jx = Jl[t][0], jy = Jl[t][1], jz = Jl[t][2];
    float* Ab = Aws + (size_t)b * (NJ * 12) + t * 12;
#pragma unroll
    for (int r = 0; r < 3; ++r) {
      const float g0 = G[t][r * 4 + 0], g1 = G[t][r * 4 + 1];
      const float g2 = G[t][r * 4 + 2], g3 = G[t][r * 4 + 3];
      Ab[r * 4 + 0] = g0; Ab[r * 4 + 1] = g1; Ab[r * 4 + 2] = g2;
      Ab[r * 4 + 3] = g3 - (g0 * jx + g1 * jy + g2 * jz);
      out_jt[(size_t)b * (NJ * 3) + t * 3 + r] = g3;
    }
  }
}

// ---------------------------------------------------------------------------
// Pack posedirs -> bf16 B-frags. grid NT_PAD*KK x 64
// Bp[nt][kk][lane][j] = pdirs[kk*32 + (lane>>4)*8 + j][nt*16 + (lane&15)]
// ---------------------------------------------------------------------------
__global__ void k_packB(const float* __restrict__ pdirs, short* __restrict__ Bp) {
  const int blk = blockIdx.x;
  const int nt = blk / KK, kk = blk % KK;
  const int lane = threadIdx.x;
  const int n = nt * 16 + (lane & 15);
  const int k0 = kk * 32 + (lane >> 4) * 8;
  short o[8];
#pragma unroll
  for (int j = 0; j < 8; ++j) {
    const int k = k0 + j;
    o[j] = f2bf((k < NP && n < V3) ? pdirs[(size_t)k * V3 + n] : 0.f);
  }
  *(bf16x8*)(Bp + ((size_t)blk * 64 + lane) * 8) = *(const bf16x8*)o;
}

// ---------------------------------------------------------------------------
// K2 fused (BISECT build): per block = 64 verts x 16 batches.
//   (0) stage A[b0..b0+16) into LDS (fp32, proven path)
//   (1) pose GEMM (MFMA, K=207) -> Cls in LDS   [stage under test]
//   (2) vph = Cls + template + shape blend (regs)
//   (3) fp32 T-build from Alds broadcasts + apply + store  [round-4 proven]
// grid (XBLK, BTILES) x 256
// ---------------------------------------------------------------------------
__global__ void __launch_bounds__(256) k2_fused(
    const short* __restrict__ Ap, const short* __restrict__ Bp,
    const float* __restrict__ Aws, const float* __restrict__ shape,
    const float* __restrict__ vtem, const float* __restrict__ sdirs,
    const float* __restrict__ wgt, float* __restrict__ verts) {
  __shared__ float Cls[16 * TSTR];        // 12.5 KB
  __shared__ float Alds[16 * NJ * 12];    // 18.4 KB
  const int w = threadIdx.x >> 6, lane = threadIdx.x & 63;
  const int g = lane >> 4, c = lane & 15;
  const int x = blockIdx.x, bt = blockIdx.y;
  const int b0 = bt * 16;

  // ---- (0) A -> LDS (coalesced)
  for (int i = threadIdx.x; i < 16 * NJ * 12; i += 256)
    Alds[i] = Aws[(size_t)b0 * (NJ * 12) + i];

  // ---- (1) pose GEMM: M=16 batches, N=192 v3 (this block), K=207
  {
    const bf16x8* Av = (const bf16x8*)Ap;
    const bf16x8* Bv = (const bf16x8*)Bp;
    bf16x8 a[KK];
#pragma unroll
    for (int kk = 0; kk < KK; ++kk) a[kk] = Av[(size_t)(bt * KK + kk) * 64 + lane];
#pragma unroll
    for (int s = 0; s < 3; ++s) {
      const int nt_g = x * 12 + w * 3 + s;
      f32x4 acc = {0.f, 0.f, 0.f, 0.f};
#pragma unroll
      for (int kk = 0; kk < KK; ++kk) {
        const bf16x8 bfrag = Bv[(size_t)(nt_g * KK + kk) * 64 + lane];
        acc = __builtin_amdgcn_mfma_f32_16x16x32_bf16(a[kk], bfrag, acc, 0, 0, 0);
      }
#pragma unroll
      for (int r = 0; r < 4; ++r)   // row = batch-local 4g+r, col = v3-local
        Cls[(4 * g + r) * TSTR + (w * 3 + s) * 16 + c] = acc[r];
    }
  }
  __syncthreads();

  // ---- (2) vph = Cls + template + shape blend
  const int v = x * 64 + lane;
  const int vv = v < NV ? v : (NV - 1);
  float vph[4][3];
  {
    const float t0 = vtem[vv * 3 + 0], t1 = vtem[vv * 3 + 1], t2 = vtem[vv * 3 + 2];
#pragma unroll
    for (int i = 0; i < 4; ++i) {
      const int bl = w + 4 * i;
      vph[i][0] = Cls[bl * TSTR + lane * 3 + 0] + t0;
      vph[i][1] = Cls[bl * TSTR + lane * 3 + 1] + t1;
      vph[i][2] = Cls[bl * TSTR + lane * 3 + 2] + t2;
    }
  }
#pragma unroll
  for (int k = 0; k < 10; ++k) {
    const float d0 = sdirs[(size_t)k * V3 + vv * 3 + 0];
    const float d1 = sdirs[(size_t)k * V3 + vv * 3 + 1];
    const float d2 = sdirs[(size_t)k * V3 + vv * 3 + 2];
#pragma unroll
    for (int i = 0; i < 4; ++i) {
      const float s = shape[(b0 + w + 4 * i) * 10 + k];  // wave-uniform scalar
      vph[i][0] += s * d0; vph[i][1] += s * d1; vph[i][2] += s * d2;
    }
  }

  // ---- (3) fp32 skinning (round-4 proven): T = sum_j w[j] * Alds[bl][j][:]
  float wj[NJ];
#pragma unroll
  for (int j = 0; j < NJ; ++j) wj[j] = wgt[vv * NJ + j];  // 96B contiguous

  float T[4][12];
#pragma unroll
  for (int i = 0; i < 4; ++i)
#pragma unroll
    for (int k = 0; k < 12; ++k) T[i][k] = 0.f;

#pragma unroll
  for (int j = 0; j < NJ; ++j) {
    const float wv_ = wj[j];
#pragma unroll
    for (int i = 0; i < 4; ++i) {
      const int bl = w + 4 * i;   // wave-uniform -> broadcast ds_read_b128
      const f32x4 a0 = *(const f32x4*)&Alds[bl * (NJ * 12) + j * 12 + 0];
      const f32x4 a1 = *(const f32x4*)&Alds[bl * (NJ * 12) + j * 12 + 4];
      const f32x4 a2 = *(const f32x4*)&Alds[bl * (NJ * 12) + j * 12 + 8];
#pragma unroll
      for (int k = 0; k < 4; ++k) {
        T[i][k + 0] += wv_ * a0[k];
        T[i][k + 4] += wv_ * a1[k];
        T[i][k + 8] += wv_ * a2[k];
      }
    }
  }
  if (v < NV) {
#pragma unroll
    for (int i = 0; i < 4; ++i) {
      const int bl = w + 4 * i;
      const float X = vph[i][0], Y = vph[i][1], Z = vph[i][2];
      const size_t o = (size_t)(b0 + bl) * V3 + (size_t)v * 3;
      verts[o + 0] = T[i][0] * X + T[i][1] * Y + T[i][2]  * Z + T[i][3];
      verts[o + 1] = T[i][4] * X + T[i][5] * Y + T[i][6]  * Z + T[i][7];
      verts[o + 2] = T[i][8] * X + T[i][9] * Y + T[i][10] * Z + T[i][11];
    }
  }
}

// ---------------------------------------------------------------------------
// K3: joints[b,r,c] = sum_v verts[b,v,c] * joint_regressor[v,r]
// grid BATCH x 256
// ---------------------------------------------------------------------------
__global__ void k3_joints(const float* __restrict__ verts,
                          const float* __restrict__ jr2,
                          float* __restrict__ out_joints) {
  const int b = blockIdx.x;
  float a[NR * 3];
#pragma unroll
  for (int q = 0; q < NR * 3; ++q) a[q] = 0.f;
  for (int v = threadIdx.x; v < NV; v += 256) {
    const size_t o = (size_t)b * V3 + (size_t)v * 3;
    const float x = verts[o + 0];
    const float y = verts[o + 1];
    const float z = verts[o + 2];
#pragma unroll
    for (int r = 0; r < NR; ++r) {
      const float w = jr2[v * NR + r];
      a[r * 3 + 0] += w * x; a[r * 3 + 1] += w * y; a[r * 3 + 2] += w * z;
    }
  }
  __shared__ float red[4][NR * 3];
  const int lane = threadIdx.x & 63, wv = threadIdx.x >> 6;
#pragma unroll
  for (int q = 0; q < NR * 3; ++q) {
    float x = a[q];
#pragma unroll
    for (int off = 32; off >= 1; off >>= 1) x += __shfl_down(x, off);
    if (lane == 0) red[wv][q] = x;
  }
  __syncthreads();
  if (threadIdx.x < NR * 3) {
    const float s = red[0][threadIdx.x] + red[1][threadIdx.x] +
                    red[2][threadIdx.x] + red[3][threadIdx.x];
    out_joints[(size_t)b * (NR * 3) + threadIdx.x] = s;
  }
}

// ---------------------------------------------------------------------------
// Workspace: 4096 + Aws 1,179,648 + Ap 458,752 + Bp 9,289,728 = 10,932,224 B
// — under the >=11,780,096 B bound proven by round 4's pass.
// ---------------------------------------------------------------------------
extern "C" void kernel_launch(void* const* d_in, const int* in_sizes, int n_in,
                              void* d_out, int out_size, void* d_ws, size_t ws_size,
                              hipStream_t stream) {
  const float* shape = (const float*)d_in[0];
  const float* pose  = (const float*)d_in[1];
  const float* vtem  = (const float*)d_in[2];
  const float* sdirs = (const float*)d_in[3];
  const float* jreg  = (const float*)d_in[4];
  const float* pdirs = (const float*)d_in[5];
  const float* wgt   = (const float*)d_in[6];
  const float* jr2   = (const float*)d_in[7];
  const int*   par   = (const int*)d_in[8];

  float* ws  = (float*)d_ws;
  float* SDJ = ws;                              // 720 floats
  float* VTJ = ws + 720;                        // 72 floats (region padded to 1024)
  float* Aws = ws + 1024;                       // B*288 fp32 = 294,912 floats
  short* Ap  = (short*)(Aws + BATCH * NJ * 12); // 229,376 shorts
  short* Bp  = Ap + (size_t)BTILES * KK * 64 * 8; // 4,644,864 shorts

  float* out        = (float*)d_out;
  float* out_verts  = out;                                  // B*V*3
  float* out_joints = out + (size_t)BATCH * NV * 3;         // B*19*3
  float* out_jt     = out_joints + (size_t)BATCH * NR * 3;  // B*24*3

  k_packB<<<dim3(NT_PAD * KK), dim3(64), 0, stream>>>(pdirs, Bp);
  k0_precompute<<<dim3(72), dim3(256), 0, stream>>>(sdirs, vtem, jreg, SDJ, VTJ);
  k1_chain<<<dim3(BATCH), dim3(128), 0, stream>>>(shape, pose, par, SDJ, VTJ, Ap, Aws, out_jt);
  k2_fused<<<dim3(XBLK, BTILES), dim3(256), 0, stream>>>(
      Ap, Bp, Aws, shape, vtem, sdirs, wgt, out_verts);
  k3_joints<<<dim3(BATCH), dim3(256), 0, stream>>>(out_verts, jr2, out_joints);
}